// Round 4
// baseline (400.019 us; speedup 1.0000x reference)
//
#include <hip/hip_runtime.h>
#include <math.h>

#define B_ 4
#define L_ 5
#define P_ 1024
#define C_ 256
#define TOK (B_ * L_ * P_)   // 20480

// ---- workspace layout (short/float indices; total ~36 MB, proven budget >=39 MB) ----
// pf: pre-projected feature pyramids, bf16 (B, HW, 32) per level
#define PF0_S 0u
#define PF1_S 2097152u
#define PF2_S 2621440u
#define PF3_S 2752512u
#define PF4_S 2785280u        // end 2818048 shorts
#define WTS_F 1409024u        // float idx (== short 2818048): TOK*32
#define POSS_F 2064384u       // float idx: TOK*64  (ends float 3375104)
// u (TOK*512 shorts) overlays shorts [0, 10485760) — pf/wts/poss dead by then
#define U_S   0u
#define H1_S  10485760u       // TOK*256 shorts (reused as h2)
#define S_S   15728640u       // TOK*96 shorts
#define WC_S  17694720u       // 96*256
#define W1T_S 17719296u       // 512*256
#define W2T_S 17850368u       // 256*512 (ends 17981440)
#define BCAT_F 8990720u       // float idx (== short 17981440): 96 floats

typedef short bf16x8 __attribute__((ext_vector_type(8)));
typedef float f32x4  __attribute__((ext_vector_type(4)));

__device__ __forceinline__ unsigned short f2bf(float f) {
  unsigned u = __float_as_uint(f);
  unsigned r = (u + 0x7fffu + ((u >> 16) & 1u)) >> 16;   // RNE
  return (unsigned short)r;
}
__device__ __forceinline__ float bf2f(unsigned short u) {
  return __uint_as_float((unsigned)u << 16);
}

__device__ __forceinline__ float block_sum256(float v, float* red, int c) {
  red[c] = v; __syncthreads();
  for (int s = 128; s > 0; s >>= 1) {
    if (c < s) red[c] += red[c + s];
    __syncthreads();
  }
  float r = red[0];
  __syncthreads();
  return r;
}

__global__ void copy_x0(const float* __restrict__ x, float* __restrict__ out) {
  int i = blockIdx.x * 256 + threadIdx.x;
  int b = i / (P_ * C_);
  int r = i - b * (P_ * C_);
  size_t off = (size_t)b * 6 * P_ * C_ + r;
  out[off] = x[off];
}

// LN1 over (xq + x0) -> h1 bf16.  grid TOK x 256.
__global__ void ln1_h(const float* __restrict__ x,
                      const float* __restrict__ g, const float* __restrict__ bt,
                      unsigned short* __restrict__ h1) {
  __shared__ float red[C_];
  int t = blockIdx.x;
  int b = t / (L_ * P_);
  int r = t - b * (L_ * P_);
  int l = r / P_;
  int p = r - l * P_;
  int c = threadIdx.x;
  size_t xq_off = (((size_t)b * 6 + (l + 1)) * P_ + p) * C_;
  size_t x0_off = (((size_t)b * 6) * P_ + p) * C_;
  float v = x[xq_off + c] + x[x0_off + c];
  float mean = block_sum256(v, red, c) * (1.0f / C_);
  float dv = v - mean;
  float var = block_sum256(dv * dv, red, c) * (1.0f / C_);
  float h = dv * rsqrtf(var + 1e-5f) * g[c] + bt[c];
  h1[(size_t)t * C_ + c] = f2bf(h);
}

// LN2 over xq2 (d_out[:,1:]) -> h2 bf16.  grid TOK x 256.
__global__ void ln2_h(const float* __restrict__ out,
                      const float* __restrict__ g, const float* __restrict__ bt,
                      unsigned short* __restrict__ h2) {
  __shared__ float red[C_];
  int t = blockIdx.x;
  int b = t / (L_ * P_);
  int r = t - b * (L_ * P_);
  int l = r / P_;
  int p = r - l * P_;
  int c = threadIdx.x;
  size_t o = (((size_t)b * 6 + (l + 1)) * P_ + p) * C_;
  float v = out[o + c];
  float mean = block_sum256(v, red, c) * (1.0f / C_);
  float dv = v - mean;
  float var = block_sum256(dv * dv, red, c) * (1.0f / C_);
  float h = dv * rsqrtf(var + 1e-5f) * g[c] + bt[c];
  h2[(size_t)t * C_ + c] = f2bf(h);
}

// weight prep: W1T, W2T, Wc (96x256), bcat (96 fp32).
__global__ void prep_all(const float* __restrict__ f1W, const float* __restrict__ f2W,
                         const float* __restrict__ awW, const float* __restrict__ soW,
                         const float* __restrict__ awb, const float* __restrict__ sob,
                         unsigned short* __restrict__ W1T, unsigned short* __restrict__ W2T,
                         unsigned short* __restrict__ Wc, float* __restrict__ bcat) {
  int i = blockIdx.x * 256 + threadIdx.x;
  if (i < 131072) {                       // W1T[n*256+k] = f1W[k*512+n]
    int n = i >> 8, k = i & 255;
    W1T[i] = f2bf(f1W[k * 512 + n]);
  } else if (i < 262144) {                // W2T[n*512+k] = f2W[k*256+n]
    int j = i - 131072;
    int n = j >> 9, k = j & 511;
    W2T[j] = f2bf(f2W[k * 256 + n]);
  } else if (i < 286720) {                // Wc[n*256+k]
    int j = i - 262144;
    int n = j >> 8, k = j & 255;
    Wc[j] = f2bf(n < 32 ? awW[k * 32 + n] : soW[k * 64 + (n - 32)]);
  } else if (i < 286816) {
    int j = i - 286720;
    bcat[j] = j < 32 ? awb[j] : sob[j - 32];
  }
}

// Pre-projection: pf[b,hw,d0..d0+ND) = sum_c feat[b,c,hw] * eW[c*32+d]  (fp32 acc -> bf16)
template<int ND>
__device__ __forceinline__ void proj_body(const float* __restrict__ fb,
                                          const float* __restrict__ eW,
                                          int Cl, int HW, int d0,
                                          unsigned short* __restrict__ dst) {
  float acc[ND];
  #pragma unroll
  for (int d = 0; d < ND; ++d) acc[d] = 0.f;
  for (int c = 0; c < Cl; ++c) {
    float f = fb[(size_t)c * HW];
    const float* wr = eW + c * 32 + d0;   // uniform -> scalar loads
    #pragma unroll
    for (int d = 0; d < ND; ++d) acc[d] = fmaf(f, wr[d], acc[d]);
  }
  #pragma unroll
  for (int d = 0; d < ND; ++d) dst[d] = f2bf(acc[d]);
}

// grid 384 blocks x 256.  L0:0-255, L1:256-319, L2:320-351, L3:352-367, L4:368-383
__global__ __launch_bounds__(256) void proj_feat_k(
    const float* __restrict__ feat0, const float* __restrict__ feat1,
    const float* __restrict__ feat2, const float* __restrict__ feat3,
    const float* __restrict__ feat4,
    const float* __restrict__ e0W, const float* __restrict__ e1W,
    const float* __restrict__ e2W, const float* __restrict__ e3W,
    const float* __restrict__ e4W,
    unsigned short* __restrict__ pf) {
  int blk = blockIdx.x, tid = threadIdx.x;
  const float* feat; const float* eW; int Cl, HW, DS, lblk; unsigned pfo;
  if (blk < 256)      { feat = feat0; eW = e0W; Cl = 64;  HW = 16384; DS = 1; pfo = PF0_S; lblk = blk; }
  else if (blk < 320) { feat = feat1; eW = e1W; Cl = 128; HW = 4096;  DS = 1; pfo = PF1_S; lblk = blk - 256; }
  else if (blk < 352) { feat = feat2; eW = e2W; Cl = 256; HW = 1024;  DS = 2; pfo = PF2_S; lblk = blk - 320; }
  else if (blk < 368) { feat = feat3; eW = e3W; Cl = 512; HW = 256;   DS = 4; pfo = PF3_S; lblk = blk - 352; }
  else                { feat = feat4; eW = e4W; Cl = 256; HW = 256;   DS = 4; pfo = PF4_S; lblk = blk - 368; }
  int i = lblk * 256 + tid;
  int BHW = B_ * HW;
  int dpart = i / BHW;
  int hwi = i - dpart * BHW;
  int b = hwi / HW, hw = hwi - b * HW;
  const float* fb = feat + (size_t)b * Cl * HW + hw;
  int ND = 32 / DS, d0 = dpart * ND;
  unsigned short* dst = pf + pfo + (size_t)hwi * 32 + d0;
  if (DS == 1)      proj_body<32>(fb, eW, Cl, HW, d0, dst);
  else if (DS == 2) proj_body<16>(fb, eW, Cl, HW, d0, dst);
  else              proj_body<8> (fb, eW, Cl, HW, d0, dst);
}

// softmax over NS=4 -> wts; tanh + ref -> poss.  grid TOK x 128.
__global__ void postproc(const unsigned short* __restrict__ S, const float* __restrict__ ref,
                         float* __restrict__ wts, float* __restrict__ poss) {
  int t = blockIdx.x;
  int c = threadIdx.x;
  int b = t / (L_ * P_);
  int p = t & (P_ - 1);
  if (c < 32) {
    int g4 = (c >> 2) << 2;
    float s0 = bf2f(S[(size_t)t * 96 + g4 + 0]);
    float s1 = bf2f(S[(size_t)t * 96 + g4 + 1]);
    float s2 = bf2f(S[(size_t)t * 96 + g4 + 2]);
    float s3 = bf2f(S[(size_t)t * 96 + g4 + 3]);
    float m = fmaxf(fmaxf(s0, s1), fmaxf(s2, s3));
    float den = expf(s0 - m) + expf(s1 - m) + expf(s2 - m) + expf(s3 - m);
    float sc = bf2f(S[(size_t)t * 96 + c]);
    wts[(size_t)t * 32 + c] = expf(sc - m) / den;
  } else if (c < 96) {
    int j = c - 32;
    float sv = bf2f(S[(size_t)t * 96 + 32 + j]);
    poss[(size_t)t * 64 + j] = tanhf(sv) + ref[((size_t)b * P_ + p) * 2 + (j & 1)];
  }
}

// Sampling in projected space + residual.  grid TOK/4 x 256 (4 tokens/block).
__global__ __launch_bounds__(256) void sample_comb(
    const float* __restrict__ x, const unsigned short* __restrict__ pf,
    const float* __restrict__ wts, const float* __restrict__ poss,
    const float* __restrict__ e0b, const float* __restrict__ e1b,
    const float* __restrict__ e2b, const float* __restrict__ e3b,
    const float* __restrict__ e4b,
    float* __restrict__ out) {
  __shared__ float coef[512];
  __shared__ int   hwid[512];
  int blk = blockIdx.x;
  int t0 = blk * 4;
  int b = t0 / (L_ * P_);
  int r = t0 - b * (L_ * P_);
  int l = r >> 10;
  int p0 = r & 1023;
  int tid = threadIdx.x;

  int Hl; unsigned pfo; const float* eb;
  if (l == 0)      { Hl = 128; pfo = PF0_S; eb = e0b; }
  else if (l == 1) { Hl = 64;  pfo = PF1_S; eb = e1b; }
  else if (l == 2) { Hl = 32;  pfo = PF2_S; eb = e2b; }
  else if (l == 3) { Hl = 16;  pfo = PF3_S; eb = e3b; }
  else             { Hl = 16;  pfo = PF4_S; eb = e4b; }

  if (tid < 128) {
    int tl = tid >> 5, s = tid & 31;
    int t = t0 + tl;
    float aw = wts[(size_t)t * 32 + s];
    float px = poss[(size_t)t * 64 + s * 2 + 0];
    float py = poss[(size_t)t * 64 + s * 2 + 1];
    float Wm = (float)(Hl - 1);
    float gx = fminf(fmaxf((px + 1.0f) * 0.5f * Wm, 0.0f), Wm);
    float gy = fminf(fmaxf((py + 1.0f) * 0.5f * Wm, 0.0f), Wm);
    float x0f = floorf(gx), y0f = floorf(gy);
    int x0 = (int)x0f, y0 = (int)y0f;
    int x1 = min(x0 + 1, Hl - 1), y1 = min(y0 + 1, Hl - 1);
    float wx = gx - x0f, wy = gy - y0f;
    int base = tid * 4;   // == tl*128 + s*4
    hwid[base + 0] = y0 * Hl + x0; coef[base + 0] = aw * (1.f - wx) * (1.f - wy);
    hwid[base + 1] = y0 * Hl + x1; coef[base + 1] = aw * wx * (1.f - wy);
    hwid[base + 2] = y1 * Hl + x0; coef[base + 2] = aw * (1.f - wx) * wy;
    hwid[base + 3] = y1 * Hl + x1; coef[base + 3] = aw * wx * wy;
  }
  __syncthreads();

  int h = tid >> 5, d = tid & 31;
  const unsigned short* pfb = pf + pfo + (size_t)b * (Hl * Hl) * 32;
  float bv = eb[d];
  #pragma unroll
  for (int tk = 0; tk < 4; ++tk) {
    int cb = tk * 128 + h * 16;
    float acc = 0.f;
    #pragma unroll
    for (int k = 0; k < 16; ++k)
      acc += coef[cb + k] * bf2f(pfb[(size_t)hwid[cb + k] * 32 + d]);
    int p = p0 + tk;
    size_t o = (((size_t)b * 6 + l + 1) * P_ + p) * C_ + h * 32 + d;
    out[o] = x[o] + acc + bv;
  }
}

// bf16 MFMA GEMM, 64x64 tile, BK=64, N-guarded.  A:(M,K) bf16.  Bt:(N,K) bf16.
// MODE 0: outU = bf16(gelu(acc+bias))  MODE 1: outF[remap] += acc+bias  MODE 2: outU = bf16(acc+bias)
template<int MODE>
__global__ __launch_bounds__(256) void gemm_bf16(
    const unsigned short* __restrict__ A, const unsigned short* __restrict__ Bt,
    const float* __restrict__ bias, unsigned short* __restrict__ outU,
    float* __restrict__ outF, int N, int K) {
  constexpr int LDK = 72;
  __shared__ unsigned short Al[64 * LDK];
  __shared__ unsigned short Bl[64 * LDK];
  int m0 = blockIdx.x * 64, n0 = blockIdx.y * 64;
  int tid = threadIdx.x;
  int w = tid >> 6, lane = tid & 63;
  int q = lane >> 4, ml = lane & 15;
  int lr = tid >> 3;
  int lk = (tid & 7) * 8;

  f32x4 acc[4];
  #pragma unroll
  for (int i = 0; i < 4; i++) acc[i] = (f32x4){0.f, 0.f, 0.f, 0.f};

  int nr0 = min(n0 + lr, N - 1);
  int nr1 = min(n0 + 32 + lr, N - 1);

  for (int k0 = 0; k0 < K; k0 += 64) {
    int4 a0 = *(const int4*)(A + (size_t)(m0 + lr) * K + k0 + lk);
    int4 a1 = *(const int4*)(A + (size_t)(m0 + 32 + lr) * K + k0 + lk);
    int4 b0 = *(const int4*)(Bt + (size_t)nr0 * K + k0 + lk);
    int4 b1 = *(const int4*)(Bt + (size_t)nr1 * K + k0 + lk);
    __syncthreads();
    *(int4*)(Al + lr * LDK + lk) = a0;
    *(int4*)(Al + (32 + lr) * LDK + lk) = a1;
    *(int4*)(Bl + lr * LDK + lk) = b0;
    *(int4*)(Bl + (32 + lr) * LDK + lk) = b1;
    __syncthreads();
    #pragma unroll
    for (int ks = 0; ks < 2; ks++) {
      bf16x8 af = *(const bf16x8*)(Al + (w * 16 + ml) * LDK + ks * 32 + q * 8);
      #pragma unroll
      for (int nt = 0; nt < 4; nt++) {
        bf16x8 bf = *(const bf16x8*)(Bl + (nt * 16 + ml) * LDK + ks * 32 + q * 8);
        acc[nt] = __builtin_amdgcn_mfma_f32_16x16x32_bf16(af, bf, acc[nt], 0, 0, 0);
      }
    }
  }

  #pragma unroll
  for (int nt = 0; nt < 4; nt++) {
    int n = n0 + nt * 16 + ml;
    if (n >= N) continue;
    float bv = bias[n];
    #pragma unroll
    for (int rr = 0; rr < 4; rr++) {
      int m = m0 + w * 16 + q * 4 + rr;
      float v = acc[nt][rr] + bv;
      if (MODE == 0) {
        v = 0.5f * v * (1.0f + erff(v * 0.70710678118654752f));
        outU[(size_t)m * N + n] = f2bf(v);
      } else if (MODE == 2) {
        outU[(size_t)m * N + n] = f2bf(v);
      } else {
        int s = m >> 10;
        int p = m & 1023;
        int bb = s / 5, ll = s - bb * 5;
        size_t o = (((size_t)bb * 6 + ll + 1) * P_ + p) * C_ + n;
        outF[o] += v;
      }
    }
  }
}

extern "C" void kernel_launch(void* const* d_in, const int* in_sizes, int n_in,
                              void* d_out, int out_size, void* d_ws, size_t ws_size,
                              hipStream_t stream) {
  const float* x     = (const float*)d_in[0];
  const float* ref   = (const float*)d_in[1];
  const float* feat0 = (const float*)d_in[2];
  const float* feat1 = (const float*)d_in[3];
  const float* feat2 = (const float*)d_in[4];
  const float* feat3 = (const float*)d_in[5];
  const float* feat4 = (const float*)d_in[6];
  const float* n1g   = (const float*)d_in[7];
  const float* n1b   = (const float*)d_in[8];
  const float* awW   = (const float*)d_in[9];
  const float* awb   = (const float*)d_in[10];
  const float* soW   = (const float*)d_in[11];
  const float* sob   = (const float*)d_in[12];
  const float* e0W   = (const float*)d_in[13];
  const float* e0b   = (const float*)d_in[14];
  const float* e1W   = (const float*)d_in[15];
  const float* e1b   = (const float*)d_in[16];
  const float* e2W   = (const float*)d_in[17];
  const float* e2b   = (const float*)d_in[18];
  const float* e3W   = (const float*)d_in[19];
  const float* e3b   = (const float*)d_in[20];
  const float* e4W   = (const float*)d_in[21];
  const float* e4b   = (const float*)d_in[22];
  const float* n2g   = (const float*)d_in[23];
  const float* n2b   = (const float*)d_in[24];
  const float* f1W   = (const float*)d_in[25];
  const float* f1b   = (const float*)d_in[26];
  const float* f2W   = (const float*)d_in[27];
  const float* f2b   = (const float*)d_in[28];

  float* wsf = (float*)d_ws;
  unsigned short* ws16 = (unsigned short*)d_ws;
  unsigned short* pf  = ws16;          // levels at PF*_S offsets
  float* wts  = wsf + WTS_F;
  float* poss = wsf + POSS_F;
  unsigned short* u   = ws16 + U_S;    // overlays pf/wts/poss (dead by MLP)
  unsigned short* h1  = ws16 + H1_S;   // also h2
  unsigned short* S   = ws16 + S_S;
  unsigned short* Wc  = ws16 + WC_S;
  unsigned short* W1T = ws16 + W1T_S;
  unsigned short* W2T = ws16 + W2T_S;
  float* bcat = wsf + BCAT_F;
  float* out = (float*)d_out;

  // 1) pre-project feature pyramids: pf[b,hw,0:32] bf16
  proj_feat_k<<<384, 256, 0, stream>>>(feat0, feat1, feat2, feat3, feat4,
                                       e0W, e1W, e2W, e3W, e4W, pf);

  // 2) weight prep
  prep_all<<<1121, 256, 0, stream>>>(f1W, f2W, awW, soW, awb, sob, W1T, W2T, Wc, bcat);

  // 3) token 0 passthrough
  copy_x0<<<(B_ * P_ * C_) / 256, 256, 0, stream>>>(x, out);

  // 4) LN1 -> h1 bf16
  ln1_h<<<TOK, 256, 0, stream>>>(x, n1g, n1b, h1);

  // 5) scores GEMM: S = h1 @ Wc + bcat   (M=20480, N=96, K=256)
  gemm_bf16<2><<<dim3(320, 2), 256, 0, stream>>>(h1, Wc, bcat, S, nullptr, 96, 256);

  // 6) softmax / tanh+ref
  postproc<<<TOK, 128, 0, stream>>>(S, ref, wts, poss);

  // 7) sample in projected space + residual -> out[:,1:]
  sample_comb<<<TOK / 4, 256, 0, stream>>>(x, pf, wts, poss,
                                           e0b, e1b, e2b, e3b, e4b, out);

  // 8) LN2 -> h2 (reuses h1 buffer)
  ln2_h<<<TOK, 256, 0, stream>>>(out, n2g, n2b, h1);

  // 9) MLP GEMM1: u = gelu(h2 @ W1 + b1)   (M=20480, N=512, K=256)
  gemm_bf16<0><<<dim3(320, 8), 256, 0, stream>>>(h1, W1T, f1b, u, nullptr, 512, 256);

  // 10) MLP GEMM2: out += u @ W2 + b2      (M=20480, N=256, K=512)
  gemm_bf16<1><<<dim3(320, 4), 256, 0, stream>>>(u, W2T, f2b, nullptr, out, 256, 512);
}

// Round 5
// 256.796 us; speedup vs baseline: 1.5577x; 1.5577x over previous
//
#include <hip/hip_runtime.h>
#include <math.h>

#define B_ 4
#define L_ 5
#define P_ 1024
#define C_ 256
#define TOK (B_ * L_ * P_)   // 20480

// ---- workspace layout (short/float indices) ----
// pf: pre-projected feature pyramids, bf16 (B, HW, 32) per level
#define PF0_S 0u
#define PF1_S 2097152u
#define PF2_S 2621440u
#define PF3_S 2752512u
#define PF4_S 2785280u        // end 2818048 shorts
#define WTS_F 1409024u        // float idx (== short 2818048): TOK*32
#define POSS_F 2064384u       // float idx: TOK*64  (ends float 3375104)
// u (TOK*512 shorts) overlays shorts [0, 10485760) — pf/wts/poss dead by then
#define U_S   0u
#define H1_S  10485760u       // TOK*256 shorts (reused as h2)
#define S_S   15728640u       // TOK*96 shorts
#define WC_S  17694720u       // 96*256
#define W1T_S 17719296u       // 512*256
#define W2T_S 17850368u       // 256*512 (ends 17981440)
#define BCAT_F 8990720u       // float idx (== short 17981440): 96 floats (ends short 17981632)
#define EWT_S  17981824u      // 32*(64+128+256+512+256)=38912 shorts (ends 18020736 ≈ 36 MB)

typedef short bf16x8 __attribute__((ext_vector_type(8)));
typedef float f32x4  __attribute__((ext_vector_type(4)));

__device__ __forceinline__ unsigned short f2bf(float f) {
  unsigned u = __float_as_uint(f);
  unsigned r = (u + 0x7fffu + ((u >> 16) & 1u)) >> 16;   // RNE
  return (unsigned short)r;
}
__device__ __forceinline__ float bf2f(unsigned short u) {
  return __uint_as_float((unsigned)u << 16);
}

__global__ void copy_x0(const float* __restrict__ x, float* __restrict__ out) {
  int i = blockIdx.x * 256 + threadIdx.x;
  int b = i / (P_ * C_);
  int r = i - b * (P_ * C_);
  size_t off = (size_t)b * 6 * P_ * C_ + r;
  out[off] = x[off];
}

// fused (sum, sumsq) block reduction: 64-lane butterfly + 4-wave LDS combine.
__device__ __forceinline__ void block_stats(float v, float* ra, float* rb,
                                            int tid, float* mean, float* var) {
  float a = v, s2 = v * v;
  #pragma unroll
  for (int off = 32; off > 0; off >>= 1) {
    a  += __shfl_xor(a, off);
    s2 += __shfl_xor(s2, off);
  }
  if ((tid & 63) == 0) { ra[tid >> 6] = a; rb[tid >> 6] = s2; }
  __syncthreads();
  float s  = ra[0] + ra[1] + ra[2] + ra[3];
  float ss = rb[0] + rb[1] + rb[2] + rb[3];
  float m = s * (1.0f / C_);
  *mean = m;
  *var = ss * (1.0f / C_) - m * m;
}

// LN1 over (xq + x0) -> h1 bf16.  grid TOK x 256.
__global__ void ln1_h(const float* __restrict__ x,
                      const float* __restrict__ g, const float* __restrict__ bt,
                      unsigned short* __restrict__ h1) {
  __shared__ float ra[4], rb[4];
  int t = blockIdx.x;
  int b = t / (L_ * P_);
  int r = t - b * (L_ * P_);
  int l = r >> 10;
  int p = r & 1023;
  int c = threadIdx.x;
  size_t xq_off = (((size_t)b * 6 + (l + 1)) * P_ + p) * C_;
  size_t x0_off = (((size_t)b * 6) * P_ + p) * C_;
  float v = x[xq_off + c] + x[x0_off + c];
  float mean, var;
  block_stats(v, ra, rb, c, &mean, &var);
  float h = (v - mean) * rsqrtf(var + 1e-5f) * g[c] + bt[c];
  h1[(size_t)t * C_ + c] = f2bf(h);
}

// LN2 over xq2 (d_out[:,1:]) -> h2 bf16.  grid TOK x 256.
__global__ void ln2_h(const float* __restrict__ out,
                      const float* __restrict__ g, const float* __restrict__ bt,
                      unsigned short* __restrict__ h2) {
  __shared__ float ra[4], rb[4];
  int t = blockIdx.x;
  int b = t / (L_ * P_);
  int r = t - b * (L_ * P_);
  int l = r >> 10;
  int p = r & 1023;
  int c = threadIdx.x;
  size_t o = (((size_t)b * 6 + (l + 1)) * P_ + p) * C_;
  float v = out[o + c];
  float mean, var;
  block_stats(v, ra, rb, c, &mean, &var);
  float h = (v - mean) * rsqrtf(var + 1e-5f) * g[c] + bt[c];
  h2[(size_t)t * C_ + c] = f2bf(h);
}

// weight prep: W1T, W2T, Wc (96x256), eWT (32xCl per level, K-contig), bcat.
__global__ void prep_all(const float* __restrict__ f1W, const float* __restrict__ f2W,
                         const float* __restrict__ awW, const float* __restrict__ soW,
                         const float* __restrict__ awb, const float* __restrict__ sob,
                         const float* __restrict__ e0W, const float* __restrict__ e1W,
                         const float* __restrict__ e2W, const float* __restrict__ e3W,
                         const float* __restrict__ e4W,
                         unsigned short* __restrict__ W1T, unsigned short* __restrict__ W2T,
                         unsigned short* __restrict__ Wc, unsigned short* __restrict__ eWT,
                         float* __restrict__ bcat) {
  int i = blockIdx.x * 256 + threadIdx.x;
  if (i < 131072) {                       // W1T[n*256+k] = f1W[k*512+n]
    int n = i >> 8, k = i & 255;
    W1T[i] = f2bf(f1W[k * 512 + n]);
  } else if (i < 262144) {                // W2T[n*512+k] = f2W[k*256+n]
    int j = i - 131072;
    int n = j >> 9, k = j & 511;
    W2T[j] = f2bf(f2W[k * 256 + n]);
  } else if (i < 286720) {                // Wc[n*256+k]
    int j = i - 262144;
    int n = j >> 8, k = j & 255;
    Wc[j] = f2bf(n < 32 ? awW[k * 32 + n] : soW[k * 64 + (n - 32)]);
  } else if (i < 325632) {                // eWT[base + d*Cl + c] = eW[c*32+d]
    int j = i - 286720;
    const float* eW; int Cl, base, jj;
    if (j < 2048)       { eW = e0W; Cl = 64;  base = 0;     jj = j; }
    else if (j < 6144)  { eW = e1W; Cl = 128; base = 2048;  jj = j - 2048; }
    else if (j < 14336) { eW = e2W; Cl = 256; base = 6144;  jj = j - 6144; }
    else if (j < 30720) { eW = e3W; Cl = 512; base = 14336; jj = j - 14336; }
    else                { eW = e4W; Cl = 256; base = 30720; jj = j - 30720; }
    int d = jj / Cl, c = jj & (Cl - 1);
    eWT[base + jj] = f2bf(eW[c * 32 + d]);
  } else if (i < 325728) {
    int j = i - 325632;
    bcat[j] = j < 32 ? awb[j] : sob[j - 32];
  }
}

// Pre-projection as MFMA GEMM: pf[b*HW+hw, d] = sum_c feat[b,c,hw] * eW[c,d].
// grid 1376 blocks x 256.  Per block: 64 hw-rows x N=32, K=Cl chunked by 64.
// A staged via LDS transpose (coalesced global read of feat rows).
__global__ __launch_bounds__(256) void proj_gemm(
    const float* __restrict__ f0, const float* __restrict__ f1,
    const float* __restrict__ f2, const float* __restrict__ f3,
    const float* __restrict__ f4,
    const unsigned short* __restrict__ eWT,
    unsigned short* __restrict__ pf) {
  constexpr int LDK = 72;
  __shared__ unsigned short Al[64 * LDK];   // [m=hw][k=c]
  __shared__ unsigned short Bl[32 * LDK];   // [n=d][k=c]
  int blk = blockIdx.x, tid = threadIdx.x;

  const float* feat; int Cl, HW, lt; unsigned pfo, eo;
  if (blk < 1024)      { feat = f0; Cl = 64;  HW = 16384; pfo = PF0_S; eo = 0;     lt = blk; }
  else if (blk < 1280) { feat = f1; Cl = 128; HW = 4096;  pfo = PF1_S; eo = 2048;  lt = blk - 1024; }
  else if (blk < 1344) { feat = f2; Cl = 256; HW = 1024;  pfo = PF2_S; eo = 6144;  lt = blk - 1280; }
  else if (blk < 1360) { feat = f3; Cl = 512; HW = 256;   pfo = PF3_S; eo = 14336; lt = blk - 1344; }
  else                 { feat = f4; Cl = 256; HW = 256;   pfo = PF4_S; eo = 30720; lt = blk - 1360; }
  int tpb = HW >> 6;
  int b = lt / tpb;
  int hw0 = (lt - b * tpb) * 64;
  const float* fb = feat + (size_t)b * Cl * HW;

  int cl = tid & 63, quad = tid >> 6;       // staging coords
  int w = tid >> 6, lane = tid & 63, q = lane >> 4, ml = lane & 15;

  f32x4 acc0 = (f32x4){0.f, 0.f, 0.f, 0.f};
  f32x4 acc1 = (f32x4){0.f, 0.f, 0.f, 0.f};

  for (int k0 = 0; k0 < Cl; k0 += 64) {
    if (k0) __syncthreads();
    // stage B chunk: 32 x 64 (K-contig rows)
    { int rr = tid >> 3, kc = (tid & 7) * 8;
      *(int4*)(Bl + rr * LDK + kc) = *(const int4*)(eWT + eo + (size_t)rr * Cl + k0 + kc); }
    // stage A chunk transposed: thread (cl,quad) reads 16 floats of feat row c=k0+cl
    const float* src = fb + (size_t)(k0 + cl) * HW + hw0 + quad * 16;
    float4 v0 = *(const float4*)(src);
    float4 v1 = *(const float4*)(src + 4);
    float4 v2 = *(const float4*)(src + 8);
    float4 v3 = *(const float4*)(src + 12);
    unsigned short* ac = Al + cl;
    int mb = quad * 16;
    ac[(mb + 0)  * LDK] = f2bf(v0.x); ac[(mb + 1)  * LDK] = f2bf(v0.y);
    ac[(mb + 2)  * LDK] = f2bf(v0.z); ac[(mb + 3)  * LDK] = f2bf(v0.w);
    ac[(mb + 4)  * LDK] = f2bf(v1.x); ac[(mb + 5)  * LDK] = f2bf(v1.y);
    ac[(mb + 6)  * LDK] = f2bf(v1.z); ac[(mb + 7)  * LDK] = f2bf(v1.w);
    ac[(mb + 8)  * LDK] = f2bf(v2.x); ac[(mb + 9)  * LDK] = f2bf(v2.y);
    ac[(mb + 10) * LDK] = f2bf(v2.z); ac[(mb + 11) * LDK] = f2bf(v2.w);
    ac[(mb + 12) * LDK] = f2bf(v3.x); ac[(mb + 13) * LDK] = f2bf(v3.y);
    ac[(mb + 14) * LDK] = f2bf(v3.z); ac[(mb + 15) * LDK] = f2bf(v3.w);
    __syncthreads();
    #pragma unroll
    for (int ks = 0; ks < 2; ks++) {
      bf16x8 af = *(const bf16x8*)(Al + (w * 16 + ml) * LDK + ks * 32 + q * 8);
      bf16x8 b0 = *(const bf16x8*)(Bl + ml * LDK + ks * 32 + q * 8);
      bf16x8 b1 = *(const bf16x8*)(Bl + (16 + ml) * LDK + ks * 32 + q * 8);
      acc0 = __builtin_amdgcn_mfma_f32_16x16x32_bf16(af, b0, acc0, 0, 0, 0);
      acc1 = __builtin_amdgcn_mfma_f32_16x16x32_bf16(af, b1, acc1, 0, 0, 0);
    }
  }

  // write pf: C-layout col=lane&15, row=(lane>>4)*4+reg
  #pragma unroll
  for (int nt = 0; nt < 2; nt++) {
    f32x4 a = nt ? acc1 : acc0;
    int d = nt * 16 + ml;
    #pragma unroll
    for (int rr = 0; rr < 4; rr++) {
      int m = w * 16 + q * 4 + rr;
      pf[pfo + ((size_t)b * HW + hw0 + m) * 32 + d] = f2bf(a[rr]);
    }
  }
}

// softmax over NS=4 -> wts; tanh + ref -> poss.  grid TOK x 128.
__global__ void postproc(const unsigned short* __restrict__ S, const float* __restrict__ ref,
                         float* __restrict__ wts, float* __restrict__ poss) {
  int t = blockIdx.x;
  int c = threadIdx.x;
  int b = t / (L_ * P_);
  int p = t & (P_ - 1);
  if (c < 32) {
    int g4 = (c >> 2) << 2;
    float s0 = bf2f(S[(size_t)t * 96 + g4 + 0]);
    float s1 = bf2f(S[(size_t)t * 96 + g4 + 1]);
    float s2 = bf2f(S[(size_t)t * 96 + g4 + 2]);
    float s3 = bf2f(S[(size_t)t * 96 + g4 + 3]);
    float m = fmaxf(fmaxf(s0, s1), fmaxf(s2, s3));
    float den = expf(s0 - m) + expf(s1 - m) + expf(s2 - m) + expf(s3 - m);
    float sc = bf2f(S[(size_t)t * 96 + c]);
    wts[(size_t)t * 32 + c] = expf(sc - m) / den;
  } else if (c < 96) {
    int j = c - 32;
    float sv = bf2f(S[(size_t)t * 96 + 32 + j]);
    poss[(size_t)t * 64 + j] = tanhf(sv) + ref[((size_t)b * P_ + p) * 2 + (j & 1)];
  }
}

// Sampling in projected space + residual.  grid TOK/4 x 256 (4 tokens/block).
__global__ __launch_bounds__(256) void sample_comb(
    const float* __restrict__ x, const unsigned short* __restrict__ pf,
    const float* __restrict__ wts, const float* __restrict__ poss,
    const float* __restrict__ e0b, const float* __restrict__ e1b,
    const float* __restrict__ e2b, const float* __restrict__ e3b,
    const float* __restrict__ e4b,
    float* __restrict__ out) {
  __shared__ float coef[512];
  __shared__ int   hwid[512];
  int blk = blockIdx.x;
  int t0 = blk * 4;
  int b = t0 / (L_ * P_);
  int r = t0 - b * (L_ * P_);
  int l = r >> 10;
  int p0 = r & 1023;
  int tid = threadIdx.x;

  int Hl; unsigned pfo; const float* eb;
  if (l == 0)      { Hl = 128; pfo = PF0_S; eb = e0b; }
  else if (l == 1) { Hl = 64;  pfo = PF1_S; eb = e1b; }
  else if (l == 2) { Hl = 32;  pfo = PF2_S; eb = e2b; }
  else if (l == 3) { Hl = 16;  pfo = PF3_S; eb = e3b; }
  else             { Hl = 16;  pfo = PF4_S; eb = e4b; }

  if (tid < 128) {
    int tl = tid >> 5, s = tid & 31;
    int t = t0 + tl;
    float aw = wts[(size_t)t * 32 + s];
    float px = poss[(size_t)t * 64 + s * 2 + 0];
    float py = poss[(size_t)t * 64 + s * 2 + 1];
    float Wm = (float)(Hl - 1);
    float gx = fminf(fmaxf((px + 1.0f) * 0.5f * Wm, 0.0f), Wm);
    float gy = fminf(fmaxf((py + 1.0f) * 0.5f * Wm, 0.0f), Wm);
    float x0f = floorf(gx), y0f = floorf(gy);
    int x0 = (int)x0f, y0 = (int)y0f;
    int x1 = min(x0 + 1, Hl - 1), y1 = min(y0 + 1, Hl - 1);
    float wx = gx - x0f, wy = gy - y0f;
    int base = tid * 4;
    hwid[base + 0] = y0 * Hl + x0; coef[base + 0] = aw * (1.f - wx) * (1.f - wy);
    hwid[base + 1] = y0 * Hl + x1; coef[base + 1] = aw * wx * (1.f - wy);
    hwid[base + 2] = y1 * Hl + x0; coef[base + 2] = aw * (1.f - wx) * wy;
    hwid[base + 3] = y1 * Hl + x1; coef[base + 3] = aw * wx * wy;
  }
  __syncthreads();

  int h = tid >> 5, d = tid & 31;
  const unsigned short* pfb = pf + pfo + (size_t)b * (Hl * Hl) * 32;
  float bv = eb[d];
  #pragma unroll
  for (int tk = 0; tk < 4; ++tk) {
    int cb = tk * 128 + h * 16;
    float acc = 0.f;
    #pragma unroll
    for (int k = 0; k < 16; ++k)
      acc += coef[cb + k] * bf2f(pfb[(size_t)hwid[cb + k] * 32 + d]);
    int p = p0 + tk;
    size_t o = (((size_t)b * 6 + l + 1) * P_ + p) * C_ + h * 32 + d;
    out[o] = x[o] + acc + bv;
  }
}

// bf16 MFMA GEMM, 64x64 tile, BK=64, N-guarded.  A:(M,K) bf16.  Bt:(N,K) bf16.
// MODE 0: outU = bf16(gelu(acc+bias))  MODE 1: outF[remap] += acc+bias  MODE 2: outU = bf16(acc+bias)
template<int MODE>
__global__ __launch_bounds__(256) void gemm_bf16(
    const unsigned short* __restrict__ A, const unsigned short* __restrict__ Bt,
    const float* __restrict__ bias, unsigned short* __restrict__ outU,
    float* __restrict__ outF, int N, int K) {
  constexpr int LDK = 72;
  __shared__ unsigned short Al[64 * LDK];
  __shared__ unsigned short Bl[64 * LDK];
  int m0 = blockIdx.x * 64, n0 = blockIdx.y * 64;
  int tid = threadIdx.x;
  int w = tid >> 6, lane = tid & 63;
  int q = lane >> 4, ml = lane & 15;
  int lr = tid >> 3;
  int lk = (tid & 7) * 8;

  f32x4 acc[4];
  #pragma unroll
  for (int i = 0; i < 4; i++) acc[i] = (f32x4){0.f, 0.f, 0.f, 0.f};

  int nr0 = min(n0 + lr, N - 1);
  int nr1 = min(n0 + 32 + lr, N - 1);

  for (int k0 = 0; k0 < K; k0 += 64) {
    int4 a0 = *(const int4*)(A + (size_t)(m0 + lr) * K + k0 + lk);
    int4 a1 = *(const int4*)(A + (size_t)(m0 + 32 + lr) * K + k0 + lk);
    int4 b0 = *(const int4*)(Bt + (size_t)nr0 * K + k0 + lk);
    int4 b1 = *(const int4*)(Bt + (size_t)nr1 * K + k0 + lk);
    __syncthreads();
    *(int4*)(Al + lr * LDK + lk) = a0;
    *(int4*)(Al + (32 + lr) * LDK + lk) = a1;
    *(int4*)(Bl + lr * LDK + lk) = b0;
    *(int4*)(Bl + (32 + lr) * LDK + lk) = b1;
    __syncthreads();
    #pragma unroll
    for (int ks = 0; ks < 2; ks++) {
      bf16x8 af = *(const bf16x8*)(Al + (w * 16 + ml) * LDK + ks * 32 + q * 8);
      #pragma unroll
      for (int nt = 0; nt < 4; nt++) {
        bf16x8 bf = *(const bf16x8*)(Bl + (nt * 16 + ml) * LDK + ks * 32 + q * 8);
        acc[nt] = __builtin_amdgcn_mfma_f32_16x16x32_bf16(af, bf, acc[nt], 0, 0, 0);
      }
    }
  }

  #pragma unroll
  for (int nt = 0; nt < 4; nt++) {
    int n = n0 + nt * 16 + ml;
    if (n >= N) continue;
    float bv = bias[n];
    #pragma unroll
    for (int rr = 0; rr < 4; rr++) {
      int m = m0 + w * 16 + q * 4 + rr;
      float v = acc[nt][rr] + bv;
      if (MODE == 0) {
        v = 0.5f * v * (1.0f + erff(v * 0.70710678118654752f));
        outU[(size_t)m * N + n] = f2bf(v);
      } else if (MODE == 2) {
        outU[(size_t)m * N + n] = f2bf(v);
      } else {
        int s = m >> 10;
        int p = m & 1023;
        int bb = s / 5, ll = s - bb * 5;
        size_t o = (((size_t)bb * 6 + ll + 1) * P_ + p) * C_ + n;
        outF[o] += v;
      }
    }
  }
}

extern "C" void kernel_launch(void* const* d_in, const int* in_sizes, int n_in,
                              void* d_out, int out_size, void* d_ws, size_t ws_size,
                              hipStream_t stream) {
  const float* x     = (const float*)d_in[0];
  const float* ref   = (const float*)d_in[1];
  const float* feat0 = (const float*)d_in[2];
  const float* feat1 = (const float*)d_in[3];
  const float* feat2 = (const float*)d_in[4];
  const float* feat3 = (const float*)d_in[5];
  const float* feat4 = (const float*)d_in[6];
  const float* n1g   = (const float*)d_in[7];
  const float* n1b   = (const float*)d_in[8];
  const float* awW   = (const float*)d_in[9];
  const float* awb   = (const float*)d_in[10];
  const float* soW   = (const float*)d_in[11];
  const float* sob   = (const float*)d_in[12];
  const float* e0W   = (const float*)d_in[13];
  const float* e0b   = (const float*)d_in[14];
  const float* e1W   = (const float*)d_in[15];
  const float* e1b   = (const float*)d_in[16];
  const float* e2W   = (const float*)d_in[17];
  const float* e2b   = (const float*)d_in[18];
  const float* e3W   = (const float*)d_in[19];
  const float* e3b   = (const float*)d_in[20];
  const float* e4W   = (const float*)d_in[21];
  const float* e4b   = (const float*)d_in[22];
  const float* n2g   = (const float*)d_in[23];
  const float* n2b   = (const float*)d_in[24];
  const float* f1W   = (const float*)d_in[25];
  const float* f1b   = (const float*)d_in[26];
  const float* f2W   = (const float*)d_in[27];
  const float* f2b   = (const float*)d_in[28];

  float* wsf = (float*)d_ws;
  unsigned short* ws16 = (unsigned short*)d_ws;
  unsigned short* pf  = ws16;
  float* wts  = wsf + WTS_F;
  float* poss = wsf + POSS_F;
  unsigned short* u   = ws16 + U_S;
  unsigned short* h1  = ws16 + H1_S;
  unsigned short* S   = ws16 + S_S;
  unsigned short* Wc  = ws16 + WC_S;
  unsigned short* W1T = ws16 + W1T_S;
  unsigned short* W2T = ws16 + W2T_S;
  unsigned short* eWT = ws16 + EWT_S;
  float* bcat = wsf + BCAT_F;
  float* out = (float*)d_out;

  // 1) weight prep (eWT needed by proj_gemm)
  prep_all<<<1273, 256, 0, stream>>>(f1W, f2W, awW, soW, awb, sob,
                                     e0W, e1W, e2W, e3W, e4W,
                                     W1T, W2T, Wc, eWT, bcat);

  // 2) pre-project feature pyramids via MFMA: pf[b,hw,0:32] bf16
  proj_gemm<<<1376, 256, 0, stream>>>(feat0, feat1, feat2, feat3, feat4, eWT, pf);

  // 3) token 0 passthrough
  copy_x0<<<(B_ * P_ * C_) / 256, 256, 0, stream>>>(x, out);

  // 4) LN1 -> h1 bf16
  ln1_h<<<TOK, 256, 0, stream>>>(x, n1g, n1b, h1);

  // 5) scores GEMM: S = h1 @ Wc + bcat   (M=20480, N=96, K=256)
  gemm_bf16<2><<<dim3(320, 2), 256, 0, stream>>>(h1, Wc, bcat, S, nullptr, 96, 256);

  // 6) softmax / tanh+ref
  postproc<<<TOK, 128, 0, stream>>>(S, ref, wts, poss);

  // 7) sample in projected space + residual -> out[:,1:]
  sample_comb<<<TOK / 4, 256, 0, stream>>>(x, pf, wts, poss,
                                           e0b, e1b, e2b, e3b, e4b, out);

  // 8) LN2 -> h2 (reuses h1 buffer)
  ln2_h<<<TOK, 256, 0, stream>>>(out, n2g, n2b, h1);

  // 9) MLP GEMM1: u = gelu(h2 @ W1 + b1)   (M=20480, N=512, K=256)
  gemm_bf16<0><<<dim3(320, 8), 256, 0, stream>>>(h1, W1T, f1b, u, nullptr, 512, 256);

  // 10) MLP GEMM2: out += u @ W2 + b2      (M=20480, N=256, K=512)
  gemm_bf16<1><<<dim3(320, 4), 256, 0, stream>>>(u, W2T, f2b, nullptr, out, 256, 512);
}

// Round 6
// 238.052 us; speedup vs baseline: 1.6804x; 1.0787x over previous
//
#include <hip/hip_runtime.h>
#include <math.h>

#define B_ 4
#define L_ 5
#define P_ 1024
#define C_ 256
#define TOK (B_ * L_ * P_)   // 20480

// ---- workspace layout (short/float indices) ----
#define PF0_S 0u
#define PF1_S 2097152u
#define PF2_S 2621440u
#define PF3_S 2752512u
#define PF4_S 2785280u        // end 2818048 shorts
#define WTS_F 1409024u        // float idx (== short 2818048): TOK*32
#define POSS_F 2064384u       // float idx: TOK*64  (ends float 3375104)
// u (TOK*512 shorts) overlays shorts [0, 10485760) — pf/wts/poss dead by then
#define U_S   0u
#define H2_S  10485760u       // TOK*256 shorts
#define WC_S  17694720u       // 96*256
#define W1T_S 17719296u       // 512*256
#define W2T_S 17850368u       // 256*512 (ends 17981440)
#define BCAT_F 8990720u       // float idx (== short 17981440): 96 floats
#define EWT_S  17981824u      // 38912 shorts (ends 18020736 ≈ 36 MB)

typedef short bf16x8 __attribute__((ext_vector_type(8)));
typedef float f32x4  __attribute__((ext_vector_type(4)));

__device__ __forceinline__ unsigned short f2bf(float f) {
  unsigned u = __float_as_uint(f);
  unsigned r = (u + 0x7fffu + ((u >> 16) & 1u)) >> 16;   // RNE
  return (unsigned short)r;
}
__device__ __forceinline__ float bf2f(unsigned short u) {
  return __uint_as_float((unsigned)u << 16);
}

// weight prep + x0 passthrough.  grid 5369 x 256.
__global__ void prep_all(const float* __restrict__ x, float* __restrict__ out,
                         const float* __restrict__ f1W, const float* __restrict__ f2W,
                         const float* __restrict__ awW, const float* __restrict__ soW,
                         const float* __restrict__ awb, const float* __restrict__ sob,
                         const float* __restrict__ e0W, const float* __restrict__ e1W,
                         const float* __restrict__ e2W, const float* __restrict__ e3W,
                         const float* __restrict__ e4W,
                         unsigned short* __restrict__ W1T, unsigned short* __restrict__ W2T,
                         unsigned short* __restrict__ Wc, unsigned short* __restrict__ eWT,
                         float* __restrict__ bcat) {
  int i = blockIdx.x * 256 + threadIdx.x;
  if (i < 1048576) {                      // out[:,0] = x[:,0]
    int b = i >> 18;
    int r = i & 262143;
    size_t off = (size_t)b * 6 * P_ * C_ + r;
    out[off] = x[off];
    return;
  }
  i -= 1048576;
  if (i < 131072) {                       // W1T[n*256+k] = f1W[k*512+n]
    int n = i >> 8, k = i & 255;
    W1T[i] = f2bf(f1W[k * 512 + n]);
  } else if (i < 262144) {                // W2T[n*512+k] = f2W[k*256+n]
    int j = i - 131072;
    int n = j >> 9, k = j & 511;
    W2T[j] = f2bf(f2W[k * 256 + n]);
  } else if (i < 286720) {                // Wc[n*256+k]
    int j = i - 262144;
    int n = j >> 8, k = j & 255;
    Wc[j] = f2bf(n < 32 ? awW[k * 32 + n] : soW[k * 64 + (n - 32)]);
  } else if (i < 325632) {                // eWT[base + d*Cl + c] = eW[c*32+d]
    int j = i - 286720;
    const float* eW; int Cl, base, jj;
    if (j < 2048)       { eW = e0W; Cl = 64;  base = 0;     jj = j; }
    else if (j < 6144)  { eW = e1W; Cl = 128; base = 2048;  jj = j - 2048; }
    else if (j < 14336) { eW = e2W; Cl = 256; base = 6144;  jj = j - 6144; }
    else if (j < 30720) { eW = e3W; Cl = 512; base = 14336; jj = j - 14336; }
    else                { eW = e4W; Cl = 256; base = 30720; jj = j - 30720; }
    int d = jj / Cl, c = jj & (Cl - 1);
    eWT[base + jj] = f2bf(eW[c * 32 + d]);
  } else if (i < 325728) {
    int j = i - 325632;
    bcat[j] = j < 32 ? awb[j] : sob[j - 32];
  }
}

// Pre-projection as MFMA GEMM: pf[b*HW+hw, d] = sum_c feat[b,c,hw] * eW[c,d].
__global__ __launch_bounds__(256) void proj_gemm(
    const float* __restrict__ f0, const float* __restrict__ f1,
    const float* __restrict__ f2, const float* __restrict__ f3,
    const float* __restrict__ f4,
    const unsigned short* __restrict__ eWT,
    unsigned short* __restrict__ pf) {
  constexpr int LDK = 72;
  __shared__ unsigned short Al[64 * LDK];
  __shared__ unsigned short Bl[32 * LDK];
  int blk = blockIdx.x, tid = threadIdx.x;

  const float* feat; int Cl, HW, lt; unsigned pfo, eo;
  if (blk < 1024)      { feat = f0; Cl = 64;  HW = 16384; pfo = PF0_S; eo = 0;     lt = blk; }
  else if (blk < 1280) { feat = f1; Cl = 128; HW = 4096;  pfo = PF1_S; eo = 2048;  lt = blk - 1024; }
  else if (blk < 1344) { feat = f2; Cl = 256; HW = 1024;  pfo = PF2_S; eo = 6144;  lt = blk - 1280; }
  else if (blk < 1360) { feat = f3; Cl = 512; HW = 256;   pfo = PF3_S; eo = 14336; lt = blk - 1344; }
  else                 { feat = f4; Cl = 256; HW = 256;   pfo = PF4_S; eo = 30720; lt = blk - 1360; }
  int tpb = HW >> 6;
  int b = lt / tpb;
  int hw0 = (lt - b * tpb) * 64;
  const float* fb = feat + (size_t)b * Cl * HW;

  int cl = tid & 63, quad = tid >> 6;
  int w = tid >> 6, lane = tid & 63, q = lane >> 4, ml = lane & 15;

  f32x4 acc0 = (f32x4){0.f, 0.f, 0.f, 0.f};
  f32x4 acc1 = (f32x4){0.f, 0.f, 0.f, 0.f};

  for (int k0 = 0; k0 < Cl; k0 += 64) {
    if (k0) __syncthreads();
    { int rr = tid >> 3, kc = (tid & 7) * 8;
      *(int4*)(Bl + rr * LDK + kc) = *(const int4*)(eWT + eo + (size_t)rr * Cl + k0 + kc); }
    const float* src = fb + (size_t)(k0 + cl) * HW + hw0 + quad * 16;
    float4 v0 = *(const float4*)(src);
    float4 v1 = *(const float4*)(src + 4);
    float4 v2 = *(const float4*)(src + 8);
    float4 v3 = *(const float4*)(src + 12);
    unsigned short* ac = Al + cl;
    int mb = quad * 16;
    ac[(mb + 0)  * LDK] = f2bf(v0.x); ac[(mb + 1)  * LDK] = f2bf(v0.y);
    ac[(mb + 2)  * LDK] = f2bf(v0.z); ac[(mb + 3)  * LDK] = f2bf(v0.w);
    ac[(mb + 4)  * LDK] = f2bf(v1.x); ac[(mb + 5)  * LDK] = f2bf(v1.y);
    ac[(mb + 6)  * LDK] = f2bf(v1.z); ac[(mb + 7)  * LDK] = f2bf(v1.w);
    ac[(mb + 8)  * LDK] = f2bf(v2.x); ac[(mb + 9)  * LDK] = f2bf(v2.y);
    ac[(mb + 10) * LDK] = f2bf(v2.z); ac[(mb + 11) * LDK] = f2bf(v2.w);
    ac[(mb + 12) * LDK] = f2bf(v3.x); ac[(mb + 13) * LDK] = f2bf(v3.y);
    ac[(mb + 14) * LDK] = f2bf(v3.z); ac[(mb + 15) * LDK] = f2bf(v3.w);
    __syncthreads();
    #pragma unroll
    for (int ks = 0; ks < 2; ks++) {
      bf16x8 af = *(const bf16x8*)(Al + (w * 16 + ml) * LDK + ks * 32 + q * 8);
      bf16x8 b0 = *(const bf16x8*)(Bl + ml * LDK + ks * 32 + q * 8);
      bf16x8 b1 = *(const bf16x8*)(Bl + (16 + ml) * LDK + ks * 32 + q * 8);
      acc0 = __builtin_amdgcn_mfma_f32_16x16x32_bf16(af, b0, acc0, 0, 0, 0);
      acc1 = __builtin_amdgcn_mfma_f32_16x16x32_bf16(af, b1, acc1, 0, 0, 0);
    }
  }

  #pragma unroll
  for (int nt = 0; nt < 2; nt++) {
    f32x4 a = nt ? acc1 : acc0;
    int d = nt * 16 + ml;
    #pragma unroll
    for (int rr = 0; rr < 4; rr++) {
      int m = w * 16 + q * 4 + rr;
      pf[pfo + ((size_t)b * HW + hw0 + m) * 32 + d] = f2bf(a[rr]);
    }
  }
}

// Fused LN1 + scores GEMM (N=96) + softmax/tanh epilogue.
// grid 320 x 256: 64 tokens per block.
__global__ __launch_bounds__(256) void attn_prep(
    const float* __restrict__ x, const float* __restrict__ ref,
    const float* __restrict__ n1g, const float* __restrict__ n1b,
    const unsigned short* __restrict__ Wc, const float* __restrict__ bcat,
    float* __restrict__ wts, float* __restrict__ poss) {
  constexpr int LDA = 264;                 // 256 + 8 pad, keeps b128 aligned
  __shared__ unsigned short Al[64 * LDA];  // LN1 rows bf16
  __shared__ unsigned short Bl[96 * 72];
  __shared__ float gg[C_], bb[C_];
  int t0 = blockIdx.x * 64;
  int tid = threadIdx.x;

  gg[tid] = n1g[tid];
  bb[tid] = n1b[tid];
  __syncthreads();

  // Phase A: LN1 for 64 token rows (8 threads per row, 32 cols each)
  #pragma unroll
  for (int half = 0; half < 2; ++half) {
    int r = half * 32 + (tid >> 3);
    int c0 = (tid & 7) * 32;
    int t = t0 + r;
    int b = t / (L_ * P_);
    int rr_ = t - b * (L_ * P_);
    int l = rr_ >> 10, p = rr_ & 1023;
    const float* xq = x + (((size_t)b * 6 + (l + 1)) * P_ + p) * C_ + c0;
    const float* x0 = x + (((size_t)b * 6) * P_ + p) * C_ + c0;
    float v[32];
    float s = 0.f, s2 = 0.f;
    #pragma unroll
    for (int i = 0; i < 32; i += 4) {
      float4 a = *(const float4*)(xq + i);
      float4 z = *(const float4*)(x0 + i);
      v[i] = a.x + z.x; v[i + 1] = a.y + z.y; v[i + 2] = a.z + z.z; v[i + 3] = a.w + z.w;
      s += v[i] + v[i + 1] + v[i + 2] + v[i + 3];
      s2 += v[i] * v[i] + v[i + 1] * v[i + 1] + v[i + 2] * v[i + 2] + v[i + 3] * v[i + 3];
    }
    #pragma unroll
    for (int off = 1; off < 8; off <<= 1) {
      s += __shfl_xor(s, off);
      s2 += __shfl_xor(s2, off);
    }
    float mean = s * (1.0f / C_);
    float var = s2 * (1.0f / C_) - mean * mean;
    float rs = rsqrtf(var + 1e-5f);
    unsigned short* dst = Al + r * LDA + c0;
    #pragma unroll
    for (int i = 0; i < 32; ++i)
      dst[i] = f2bf((v[i] - mean) * rs * gg[c0 + i] + bb[c0 + i]);
  }

  // Phase B: MFMA, K=256 in 4 chunks; B restaged per chunk.
  f32x4 acc[6];
  #pragma unroll
  for (int i = 0; i < 6; ++i) acc[i] = (f32x4){0.f, 0.f, 0.f, 0.f};
  int w = tid >> 6, lane = tid & 63, q = lane >> 4, ml = lane & 15;

  for (int k0 = 0; k0 < 256; k0 += 64) {
    __syncthreads();   // Al ready (first iter) / Bl safe to overwrite
    #pragma unroll
    for (int i = 0; i < 3; ++i) {
      int idx = tid + 256 * i;               // 0..767 = 96 rows x 8
      int rw = idx >> 3, kc = (idx & 7) * 8;
      *(int4*)(Bl + rw * 72 + kc) = *(const int4*)(Wc + (size_t)rw * 256 + k0 + kc);
    }
    __syncthreads();
    #pragma unroll
    for (int ks = 0; ks < 2; ++ks) {
      bf16x8 af = *(const bf16x8*)(Al + (w * 16 + ml) * LDA + k0 + ks * 32 + q * 8);
      #pragma unroll
      for (int nt = 0; nt < 6; ++nt) {
        bf16x8 bf = *(const bf16x8*)(Bl + (nt * 16 + ml) * 72 + ks * 32 + q * 8);
        acc[nt] = __builtin_amdgcn_mfma_f32_16x16x32_bf16(af, bf, acc[nt], 0, 0, 0);
      }
    }
  }

  // Epilogue: n<32 -> softmax over 4 adjacent lanes; n>=32 -> tanh + ref.
  #pragma unroll
  for (int nt = 0; nt < 6; ++nt) {
    int n = nt * 16 + ml;
    float bv = bcat[n];
    f32x4 a = acc[nt];
    if (nt < 2) {        // n < 32: softmax groups s = n&3 live in lanes ml^1, ml^2
      #pragma unroll
      for (int rr = 0; rr < 4; ++rr) {
        float v = a[rr] + bv;
        float m1 = fmaxf(v, __shfl_xor(v, 1));
        float m = fmaxf(m1, __shfl_xor(m1, 2));
        float e = expf(v - m);
        float su = e + __shfl_xor(e, 1);
        su += __shfl_xor(su, 2);
        int t = t0 + w * 16 + q * 4 + rr;
        wts[(size_t)t * 32 + n] = e / su;
      }
    } else {
      int j = n - 32;
      #pragma unroll
      for (int rr = 0; rr < 4; ++rr) {
        float v = a[rr] + bv;
        int t = t0 + w * 16 + q * 4 + rr;
        int b = t / (L_ * P_);
        int p = t & 1023;
        poss[(size_t)t * 64 + j] = tanhf(v) + ref[((size_t)b * P_ + p) * 2 + (j & 1)];
      }
    }
  }
}

// Fused sampling + residual + LN2.  grid TOK x 256 (1 token/block, thread = channel).
__global__ __launch_bounds__(256) void sample_ln2(
    const float* __restrict__ x, const unsigned short* __restrict__ pf,
    const float* __restrict__ wts, const float* __restrict__ poss,
    const float* __restrict__ e0b, const float* __restrict__ e1b,
    const float* __restrict__ e2b, const float* __restrict__ e3b,
    const float* __restrict__ e4b,
    const float* __restrict__ n2g, const float* __restrict__ n2b,
    float* __restrict__ out, unsigned short* __restrict__ h2) {
  __shared__ float coef[128];
  __shared__ int   hwid[128];
  __shared__ float ra[4], rb[4];
  int t = blockIdx.x;
  int b = t / (L_ * P_);
  int r = t - b * (L_ * P_);
  int l = r >> 10;
  int p = r & 1023;
  int tid = threadIdx.x;

  int Hl; unsigned pfo; const float* eb;
  if (l == 0)      { Hl = 128; pfo = PF0_S; eb = e0b; }
  else if (l == 1) { Hl = 64;  pfo = PF1_S; eb = e1b; }
  else if (l == 2) { Hl = 32;  pfo = PF2_S; eb = e2b; }
  else if (l == 3) { Hl = 16;  pfo = PF3_S; eb = e3b; }
  else             { Hl = 16;  pfo = PF4_S; eb = e4b; }

  if (tid < 32) {
    int s = tid;
    float aw = wts[(size_t)t * 32 + s];
    float px = poss[(size_t)t * 64 + s * 2 + 0];
    float py = poss[(size_t)t * 64 + s * 2 + 1];
    float Wm = (float)(Hl - 1);
    float gx = fminf(fmaxf((px + 1.0f) * 0.5f * Wm, 0.0f), Wm);
    float gy = fminf(fmaxf((py + 1.0f) * 0.5f * Wm, 0.0f), Wm);
    float x0f = floorf(gx), y0f = floorf(gy);
    int x0 = (int)x0f, y0 = (int)y0f;
    int x1 = min(x0 + 1, Hl - 1), y1 = min(y0 + 1, Hl - 1);
    float wx = gx - x0f, wy = gy - y0f;
    int base = s * 4;
    hwid[base + 0] = y0 * Hl + x0; coef[base + 0] = aw * (1.f - wx) * (1.f - wy);
    hwid[base + 1] = y0 * Hl + x1; coef[base + 1] = aw * wx * (1.f - wy);
    hwid[base + 2] = y1 * Hl + x0; coef[base + 2] = aw * (1.f - wx) * wy;
    hwid[base + 3] = y1 * Hl + x1; coef[base + 3] = aw * wx * wy;
  }
  __syncthreads();

  int h = tid >> 5, d = tid & 31;
  const unsigned short* pfb = pf + pfo + (size_t)b * (Hl * Hl) * 32;
  float acc = 0.f;
  #pragma unroll
  for (int k = 0; k < 16; ++k)
    acc += coef[h * 16 + k] * bf2f(pfb[(size_t)hwid[h * 16 + k] * 32 + d]);

  size_t o = (((size_t)b * 6 + l + 1) * P_ + p) * C_ + tid;
  float v = x[o] + acc + eb[d];
  out[o] = v;

  // LN2 inline: block stats over 256 channels
  float sa = v, s2 = v * v;
  #pragma unroll
  for (int off = 32; off > 0; off >>= 1) {
    sa += __shfl_xor(sa, off);
    s2 += __shfl_xor(s2, off);
  }
  if ((tid & 63) == 0) { ra[tid >> 6] = sa; rb[tid >> 6] = s2; }
  __syncthreads();
  float s  = ra[0] + ra[1] + ra[2] + ra[3];
  float ss = rb[0] + rb[1] + rb[2] + rb[3];
  float mean = s * (1.0f / C_);
  float var = ss * (1.0f / C_) - mean * mean;
  float hh = (v - mean) * rsqrtf(var + 1e-5f) * n2g[tid] + n2b[tid];
  h2[(size_t)t * C_ + tid] = f2bf(hh);
}

// bf16 MFMA GEMM, 64x64 tile, BK=64.  A:(M,K) bf16.  Bt:(N,K) bf16.
// MODE 0: outU = bf16(gelu(acc+bias))  MODE 1: outF[remap] += acc+bias
template<int MODE>
__global__ __launch_bounds__(256) void gemm_bf16(
    const unsigned short* __restrict__ A, const unsigned short* __restrict__ Bt,
    const float* __restrict__ bias, unsigned short* __restrict__ outU,
    float* __restrict__ outF, int N, int K) {
  constexpr int LDK = 72;
  __shared__ unsigned short Al[64 * LDK];
  __shared__ unsigned short Bl[64 * LDK];
  int m0 = blockIdx.x * 64, n0 = blockIdx.y * 64;
  int tid = threadIdx.x;
  int w = tid >> 6, lane = tid & 63;
  int q = lane >> 4, ml = lane & 15;
  int lr = tid >> 3;
  int lk = (tid & 7) * 8;

  f32x4 acc[4];
  #pragma unroll
  for (int i = 0; i < 4; i++) acc[i] = (f32x4){0.f, 0.f, 0.f, 0.f};

  for (int k0 = 0; k0 < K; k0 += 64) {
    int4 a0 = *(const int4*)(A + (size_t)(m0 + lr) * K + k0 + lk);
    int4 a1 = *(const int4*)(A + (size_t)(m0 + 32 + lr) * K + k0 + lk);
    int4 b0 = *(const int4*)(Bt + (size_t)(n0 + lr) * K + k0 + lk);
    int4 b1 = *(const int4*)(Bt + (size_t)(n0 + 32 + lr) * K + k0 + lk);
    __syncthreads();
    *(int4*)(Al + lr * LDK + lk) = a0;
    *(int4*)(Al + (32 + lr) * LDK + lk) = a1;
    *(int4*)(Bl + lr * LDK + lk) = b0;
    *(int4*)(Bl + (32 + lr) * LDK + lk) = b1;
    __syncthreads();
    #pragma unroll
    for (int ks = 0; ks < 2; ks++) {
      bf16x8 af = *(const bf16x8*)(Al + (w * 16 + ml) * LDK + ks * 32 + q * 8);
      #pragma unroll
      for (int nt = 0; nt < 4; nt++) {
        bf16x8 bf = *(const bf16x8*)(Bl + (nt * 16 + ml) * LDK + ks * 32 + q * 8);
        acc[nt] = __builtin_amdgcn_mfma_f32_16x16x32_bf16(af, bf, acc[nt], 0, 0, 0);
      }
    }
  }

  #pragma unroll
  for (int nt = 0; nt < 4; nt++) {
    int n = n0 + nt * 16 + ml;
    float bv = bias[n];
    #pragma unroll
    for (int rr = 0; rr < 4; rr++) {
      int m = m0 + w * 16 + q * 4 + rr;
      float v = acc[nt][rr] + bv;
      if (MODE == 0) {
        v = 0.5f * v * (1.0f + erff(v * 0.70710678118654752f));
        outU[(size_t)m * N + n] = f2bf(v);
      } else {
        int s = m >> 10;
        int p = m & 1023;
        int bb = s / 5, ll = s - bb * 5;
        size_t o = (((size_t)bb * 6 + ll + 1) * P_ + p) * C_ + n;
        outF[o] += v;
      }
    }
  }
}

extern "C" void kernel_launch(void* const* d_in, const int* in_sizes, int n_in,
                              void* d_out, int out_size, void* d_ws, size_t ws_size,
                              hipStream_t stream) {
  const float* x     = (const float*)d_in[0];
  const float* ref   = (const float*)d_in[1];
  const float* feat0 = (const float*)d_in[2];
  const float* feat1 = (const float*)d_in[3];
  const float* feat2 = (const float*)d_in[4];
  const float* feat3 = (const float*)d_in[5];
  const float* feat4 = (const float*)d_in[6];
  const float* n1g   = (const float*)d_in[7];
  const float* n1b   = (const float*)d_in[8];
  const float* awW   = (const float*)d_in[9];
  const float* awb   = (const float*)d_in[10];
  const float* soW   = (const float*)d_in[11];
  const float* sob   = (const float*)d_in[12];
  const float* e0W   = (const float*)d_in[13];
  const float* e0b   = (const float*)d_in[14];
  const float* e1W   = (const float*)d_in[15];
  const float* e1b   = (const float*)d_in[16];
  const float* e2W   = (const float*)d_in[17];
  const float* e2b   = (const float*)d_in[18];
  const float* e3W   = (const float*)d_in[19];
  const float* e3b   = (const float*)d_in[20];
  const float* e4W   = (const float*)d_in[21];
  const float* e4b   = (const float*)d_in[22];
  const float* n2g   = (const float*)d_in[23];
  const float* n2b   = (const float*)d_in[24];
  const float* f1W   = (const float*)d_in[25];
  const float* f1b   = (const float*)d_in[26];
  const float* f2W   = (const float*)d_in[27];
  const float* f2b   = (const float*)d_in[28];

  float* wsf = (float*)d_ws;
  unsigned short* ws16 = (unsigned short*)d_ws;
  unsigned short* pf  = ws16;
  float* wts  = wsf + WTS_F;
  float* poss = wsf + POSS_F;
  unsigned short* u   = ws16 + U_S;
  unsigned short* h2  = ws16 + H2_S;
  unsigned short* Wc  = ws16 + WC_S;
  unsigned short* W1T = ws16 + W1T_S;
  unsigned short* W2T = ws16 + W2T_S;
  unsigned short* eWT = ws16 + EWT_S;
  float* bcat = wsf + BCAT_F;
  float* out = (float*)d_out;

  // 1) weight prep + x0 passthrough
  prep_all<<<5369, 256, 0, stream>>>(x, out, f1W, f2W, awW, soW, awb, sob,
                                     e0W, e1W, e2W, e3W, e4W,
                                     W1T, W2T, Wc, eWT, bcat);

  // 2) pre-project feature pyramids via MFMA
  proj_gemm<<<1376, 256, 0, stream>>>(feat0, feat1, feat2, feat3, feat4, eWT, pf);

  // 3) LN1 + scores GEMM + softmax/tanh
  attn_prep<<<320, 256, 0, stream>>>(x, ref, n1g, n1b, Wc, bcat, wts, poss);

  // 4) sample + residual + LN2 -> out[:,1:], h2
  sample_ln2<<<TOK, 256, 0, stream>>>(x, pf, wts, poss,
                                      e0b, e1b, e2b, e3b, e4b,
                                      n2g, n2b, out, h2);

  // 5) MLP GEMM1: u = gelu(h2 @ W1 + b1)   (M=20480, N=512, K=256)
  gemm_bf16<0><<<dim3(320, 8), 256, 0, stream>>>(h2, W1T, f1b, u, nullptr, 512, 256);

  // 6) MLP GEMM2: out += u @ W2 + b2       (M=20480, N=256, K=512)
  gemm_bf16<1><<<dim3(320, 4), 256, 0, stream>>>(u, W2T, f2b, nullptr, out, 256, 512);
}